// Round 17
// baseline (101.281 us; speedup 1.0000x reference)
//
#include <hip/hip_runtime.h>
#include <hip/hip_bf16.h>

// Problem constants (hardcoded from setup_inputs; n_shifts == T == 64)
#define NB   4096
#define NT   64
#define NDIM 16
#define NH1  256
#define NH2  256
#define NLAT 64
#define NKD  80
#define YROW (NT * NKD)      // 5120 floats per batch row of y / y_pred
#define KTAB 98304           // short-offset of K-power fragment table in ws
#define KSLOT 15360          // shorts per t-slot (7680 hi + 7680 lo)
#define Y0F   1081344        // short-offset of y0 A-frag table
#define HPLANE 393216        // shorts per plane: 256 mtiles x 3 kk x 64 lane x 8 e

// h LDS row stride: 264 shorts = 528 B, 16B-aligned (round-14 lesson: 268
// broke b128 alignment, 1.5x slowdown). Residual 6.3M bank-conflict counter
// is 2-way-per-phase aliasing = absorbed slack (round-14 A/B).
#define HROW 264
#define HBYTES (64 * HROW * 2)   // 33792 B per 64-token h tile

// kpow frag-image geometry: hi at [row][0..79], lo at [row][96..175]
#define FROW 184
#define FIMG_B (80 * FROW * 2)   // 29440 bytes per image

typedef __attribute__((ext_vector_type(8))) short bf16x8;
typedef __attribute__((ext_vector_type(4))) float f32x4;

#define MFMA __builtin_amdgcn_mfma_f32_16x16x32_bf16

static __device__ __forceinline__ short f2bf(float f) {
  __hip_bfloat16 b = __float2bfloat16(f);      // native RNE cast (m240)
  return __builtin_bit_cast(short, b);
}
static __device__ __forceinline__ float bf2f(short h) {
  union { unsigned u; float f; } v; v.u = ((unsigned)(unsigned short)h) << 16;
  return v.f;
}
static __device__ __forceinline__ bf16x8 pack8(float4 a, float4 b) {
  bf16x8 r;
  r[0] = f2bf(a.x); r[1] = f2bf(a.y); r[2] = f2bf(a.z); r[3] = f2bf(a.w);
  r[4] = f2bf(b.x); r[5] = f2bf(b.y); r[6] = f2bf(b.z); r[7] = f2bf(b.w);
  return r;
}

// ---------------------------------------------------------------------------
// Prep: MFMA fragment order (bf16) for 16x16x32.
// Fragment: lane l holds W[g][k] with g = l&15, k = 8*(l>>4)+e.
// ws (shorts): [0) W2f 65536 | [65536) W3f 16384 | [81920) W1f 8192
// ---------------------------------------------------------------------------
__global__ __launch_bounds__(256) void prep_kernel(const float* __restrict__ W1,
                                                   const float* __restrict__ W2,
                                                   const float* __restrict__ W3,
                                                   short* __restrict__ ws) {
  int i = blockIdx.x * 256 + threadIdx.x;   // 0..65535
  {
    int e = i & 7, l = (i >> 3) & 63, nt = (i >> 9) & 15, kk = i >> 13;
    int g = nt * 16 + (l & 15);
    int h = kk * 32 + (l >> 4) * 8 + e;
    ws[i] = f2bf(W2[g * NH1 + h]);
  }
  if (i < 16384) {
    int e = i & 7, l = (i >> 3) & 63, nt = (i >> 9) & 3, kk = i >> 11;
    int g = nt * 16 + (l & 15);
    int h = kk * 32 + (l >> 4) * 8 + e;
    ws[65536 + i] = f2bf(W3[g * NH2 + h]);
  }
  if (i < 8192) {
    int e = i & 7, l = (i >> 3) & 63, nt = i >> 9;
    int g = nt * 16 + (l & 15);
    int k = (l >> 4) * 8 + e;
    ws[81920 + i] = (k < NDIM) ? f2bf(W1[g * NDIM + k]) : (short)0;
  }
}

// ---------------------------------------------------------------------------
// MLP body (round-13 proven shape; T5 setprio around ALL MFMA clusters —
// GEMM1/2/3. Pays via cross-block wave role diversity in the fused launch).
// MODE 0: write y rows. MODE 1 (mlp0): write y0 hi/lo A-frag table at ws[Y0F].
// tid is TEAM-LOCAL (0..255); h1s is the team's private HBYTES LDS carve.
// ---------------------------------------------------------------------------
template <int XSTRIDE, int MODE>
static __device__ __forceinline__ void mlp_body(long b, const float* __restrict__ x,
                                                const float* __restrict__ b1g,
                                                const float* __restrict__ b2g,
                                                const short* __restrict__ ws,
                                                float* __restrict__ yo,
                                                short* __restrict__ y0f,
                                                short* h1s, int tid) {
  const int lane = tid & 63;
  const int w    = tid >> 6;            // 0..3
  const int l15  = lane & 15;
  const int kg   = lane >> 4;

  const short* W2f = ws;
  const short* W3f = ws + 65536;
  const short* W1f = ws + 81920;

  const float4 xv =
      *(const float4*)(x + (b * 64 + (tid >> 2)) * XSTRIDE + (tid & 3) * 4);

  // ---- x B-frags (x^T): lane holds x[tok][k0..k0+7], tok = col ----
  bf16x8 xf[4];
#pragma unroll
  for (int j = 0; j < 4; ++j) {
    const int tok = j * 16 + l15;
    bf16x8 f = {};
    if (kg < 2) {
      const float4* p = (const float4*)(x + (b * 64 + tok) * XSTRIDE + kg * 8);
      f = pack8(p[0], p[1]);
    }
    xf[j] = f;
  }

  // ---- GEMM1: D = W1 x x^T -> h1[tok][h] via packed b64 stores ----
#pragma unroll
  for (int i = 0; i < 4; ++i) {
    const int mt = w * 4 + i;
    const bf16x8 wa = *(const bf16x8*)(W1f + (mt * 64 + lane) * 8);
    const float4 bias = *(const float4*)(b1g + mt * 16 + kg * 4);
    f32x4 c[4];
    __builtin_amdgcn_s_setprio(1);
#pragma unroll
    for (int j = 0; j < 4; ++j) {
      c[j] = (f32x4){0.f, 0.f, 0.f, 0.f};
      c[j] = MFMA(wa, xf[j], c[j], 0, 0, 0);
    }
    __builtin_amdgcn_s_setprio(0);
#pragma unroll
    for (int j = 0; j < 4; ++j) {
      const int tok = j * 16 + l15;
      float v0 = c[j][0] + bias.x; v0 = v0 > 0.f ? v0 : 0.f;
      float v1 = c[j][1] + bias.y; v1 = v1 > 0.f ? v1 : 0.f;
      float v2 = c[j][2] + bias.z; v2 = v2 > 0.f ? v2 : 0.f;
      float v3 = c[j][3] + bias.w; v3 = v3 > 0.f ? v3 : 0.f;
      short4 st = {f2bf(v0), f2bf(v1), f2bf(v2), f2bf(v3)};
      *(short4*)(h1s + tok * HROW + mt * 16 + kg * 4) = st;
    }
  }
  __syncthreads();

  // ---- GEMM2: D = W2 x h1^T; K=256; acc 4mt x 4nt ----
  f32x4 acc2[4][4];
#pragma unroll
  for (int i = 0; i < 4; ++i)
#pragma unroll
    for (int j = 0; j < 4; ++j) acc2[i][j] = (f32x4){0.f, 0.f, 0.f, 0.f};

#pragma unroll 2
  for (int kk = 0; kk < 8; ++kk) {
    bf16x8 wa[4], hb[4];
#pragma unroll
    for (int i = 0; i < 4; ++i)
      wa[i] = *(const bf16x8*)(W2f + ((kk * 16 + w * 4 + i) * 64 + lane) * 8);
#pragma unroll
    for (int j = 0; j < 4; ++j)
      hb[j] = *(const bf16x8*)(h1s + (j * 16 + l15) * HROW + kk * 32 + kg * 8);
    __builtin_amdgcn_s_setprio(1);
#pragma unroll
    for (int i = 0; i < 4; ++i)
#pragma unroll
      for (int j = 0; j < 4; ++j)
        acc2[i][j] = MFMA(wa[i], hb[j], acc2[i][j], 0, 0, 0);
    __builtin_amdgcn_s_setprio(0);
  }
  __syncthreads();   // all h1 reads done -> overlay h2

#pragma unroll
  for (int i = 0; i < 4; ++i) {
    const int mt = w * 4 + i;
    const float4 bias = *(const float4*)(b2g + mt * 16 + kg * 4);
#pragma unroll
    for (int j = 0; j < 4; ++j) {
      const int tok = j * 16 + l15;
      float v0 = acc2[i][j][0] + bias.x; v0 = v0 > 0.f ? v0 : 0.f;
      float v1 = acc2[i][j][1] + bias.y; v1 = v1 > 0.f ? v1 : 0.f;
      float v2 = acc2[i][j][2] + bias.z; v2 = v2 > 0.f ? v2 : 0.f;
      float v3 = acc2[i][j][3] + bias.w; v3 = v3 > 0.f ? v3 : 0.f;
      short4 st = {f2bf(v0), f2bf(v1), f2bf(v2), f2bf(v3)};
      *(short4*)(h1s + tok * HROW + mt * 16 + kg * 4) = st;
    }
  }
  __syncthreads();

  // ---- GEMM3: D = W3 x h2^T ----
  f32x4 acc3[4];
#pragma unroll
  for (int j = 0; j < 4; ++j) acc3[j] = (f32x4){0.f, 0.f, 0.f, 0.f};
#pragma unroll 2
  for (int kk = 0; kk < 8; ++kk) {
    const bf16x8 wa = *(const bf16x8*)(W3f + ((kk * 4 + w) * 64 + lane) * 8);
    bf16x8 hb[4];
#pragma unroll
    for (int j = 0; j < 4; ++j)
      hb[j] = *(const bf16x8*)(h1s + (j * 16 + l15) * HROW + kk * 32 + kg * 8);
    __builtin_amdgcn_s_setprio(1);
#pragma unroll
    for (int j = 0; j < 4; ++j)
      acc3[j] = MFMA(wa, hb[j], acc3[j], 0, 0, 0);
    __builtin_amdgcn_s_setprio(0);
  }

  if (MODE == 0) {
    // y x-part (exact f32 from regs) + g-part (one float4 per tile)
    *(float4*)(yo + (b * 64 + (tid >> 2)) * 80 + (tid & 3) * 4) = xv;
#pragma unroll
    for (int j = 0; j < 4; ++j) {
      const int tok = j * 16 + l15;
      *(float4*)(yo + (b * 64 + tok) * 80 + 16 + w * 16 + kg * 4) =
          *(float4*)&acc3[j];
    }
  } else {
    // ---- y0 hi/lo A-frag table epilogue ----
    {
      const int t0 = tid >> 2;
      const int gmt = (int)b * 4 + (t0 >> 4);
      const int c0x = (tid & 3) * 4;
      const int lanef = (c0x >> 3) * 16 + (t0 & 15);
      short h0 = f2bf(xv.x), h1 = f2bf(xv.y), h2 = f2bf(xv.z), h3 = f2bf(xv.w);
      short4 hs = {h0, h1, h2, h3};
      short4 ls = {f2bf(xv.x - bf2f(h0)), f2bf(xv.y - bf2f(h1)),
                   f2bf(xv.z - bf2f(h2)), f2bf(xv.w - bf2f(h3))};
      const int idx = ((gmt * 3 + 0) * 64 + lanef) * 8 + (c0x & 7);
      *(short4*)(y0f + idx) = hs;
      *(short4*)(y0f + HPLANE + idx) = ls;
    }
    const int c0 = 16 + w * 16 + kg * 4;
    const int kkf = c0 >> 5;
    const int lanef = ((c0 & 31) >> 3) * 16 + l15;
#pragma unroll
    for (int j = 0; j < 4; ++j) {
      const int gmt = (int)b * 4 + j;
      short h0 = f2bf(acc3[j][0]), h1 = f2bf(acc3[j][1]);
      short h2 = f2bf(acc3[j][2]), h3 = f2bf(acc3[j][3]);
      short4 hs = {h0, h1, h2, h3};
      short4 ls = {f2bf(acc3[j][0] - bf2f(h0)), f2bf(acc3[j][1] - bf2f(h1)),
                   f2bf(acc3[j][2] - bf2f(h2)), f2bf(acc3[j][3] - bf2f(h3))};
      const int idx = ((gmt * 3 + kkf) * 64 + lanef) * 8 + (c0 & 7);
      *(short4*)(y0f + idx) = hs;
      *(short4*)(y0f + HPLANE + idx) = ls;
    }
    // zero-fill k in [80,96): kk=2, lanes 32..63 (ws is poisoned, not zeroed)
    {
      const int plane = tid & 1;
      const int lz = 32 + ((tid >> 1) & 31);
      const int gmt = (int)b * 4 + (tid >> 6);
      bf16x8 z = {};
      *(bf16x8*)(y0f + plane * HPLANE + ((gmt * 3 + 2) * 64 + lz) * 8) = z;
    }
  }
}

// ---------------------------------------------------------------------------
// kpow+mlp0 fused launch (79 blocks x 1024 threads, 147200 B LDS):
//   bid 0..62 -> kpow: K^(bid+1), 16 waves (mm tiles id += 16).
//   bid 63..78 -> mlp0 x4: four independent 256-thr teams per block, each
//               running the token-0 MLP for 64 batch rows with a private
//               HBYTES h1s carve (4 x 33792 = 135168 <= 147200).
// ---------------------------------------------------------------------------
__global__ __launch_bounds__(1024, 4) void kpow_mlp0_kernel(const float* __restrict__ Kg,
                                                            const float* __restrict__ x,
                                                            const float* __restrict__ b1g,
                                                            const float* __restrict__ b2g,
                                                            short* __restrict__ ws) {
  extern __shared__ char smem[];
  const int tid = threadIdx.x;

  if (blockIdx.x >= 63) {
    const int team = tid >> 8;           // 0..3
    const int ttid = tid & 255;
    const long b = (long)(blockIdx.x - 63) * 4 + team;   // 0..63
    mlp_body<1024, 1>(b, x, b1g, b2g, ws, nullptr, ws + Y0F,
                      (short*)(smem + team * HBYTES), ttid);
    return;
  }

  short* kA   = (short*)smem;
  short* curA = (short*)(smem + FIMG_B);
  short* curB = (short*)(smem + 2 * FIMG_B);
  short* nxtA = (short*)(smem + 3 * FIMG_B);
  short* nxtB = (short*)(smem + 4 * FIMG_B);

  const int lane = tid & 63;
  const int w    = tid >> 6;            // 0..15
  const int l15  = lane & 15;
  const int kg   = lane >> 4;
  const int t    = blockIdx.x + 1;      // 1..63

  for (int i = tid; i < 6400; i += 1024) {
    float v = Kg[i];
    int r = i / 80, c = i - r * 80;
    short hi = f2bf(v);
    short lo = f2bf(v - bf2f(hi));
    kA[r * FROW + c] = hi;        kA[r * FROW + 96 + c] = lo;
    curA[r * FROW + c] = hi;      curA[r * FROW + 96 + c] = lo;
    curB[c * FROW + r] = hi;      curB[c * FROW + 96 + r] = lo;
  }
  __syncthreads();

  auto mm = [&](const short* Ai, const short* Bi, short* DA, short* DB) {
    for (int id = w; id < 25; id += 16) {
      const int mt = id / 5, nt = id % 5;
      f32x4 acc = {0.f, 0.f, 0.f, 0.f};
#pragma unroll
      for (int kk = 0; kk < 3; ++kk) {
        const int k0 = kk * 32 + kg * 8;
        bf16x8 ah = {}, al = {}, bh = {}, bl = {};
        if (k0 < 80) {
          const short* ap = Ai + (mt * 16 + l15) * FROW + k0;
          const short* bp = Bi + (nt * 16 + l15) * FROW + k0;
          ah = *(const bf16x8*)ap;  al = *(const bf16x8*)(ap + 96);
          bh = *(const bf16x8*)bp;  bl = *(const bf16x8*)(bp + 96);
        }
        acc = MFMA(ah, bh, acc, 0, 0, 0);
        acc = MFMA(al, bh, acc, 0, 0, 0);
        acc = MFMA(ah, bl, acc, 0, 0, 0);
      }
      const int n = nt * 16 + l15;
      const int rowb = mt * 16 + kg * 4;
      short4 hs, ls;
#pragma unroll
      for (int r = 0; r < 4; ++r) {
        float v = acc[r];
        short hi = f2bf(v);
        short lo = f2bf(v - bf2f(hi));
        DA[(rowb + r) * FROW + n] = hi;
        DA[(rowb + r) * FROW + 96 + n] = lo;
        ((short*)&hs)[r] = hi;
        ((short*)&ls)[r] = lo;
      }
      *(short4*)(DB + n * FROW + rowb) = hs;
      *(short4*)(DB + n * FROW + 96 + rowb) = ls;
    }
    __syncthreads();
  };

  const int h = 31 - __clz(t);
  for (int bit = h - 1; bit >= 0; --bit) {
    mm(curA, curB, nxtA, nxtB);                               // square
    { short* p;
      p = curA; curA = nxtA; nxtA = p;
      p = curB; curB = nxtB; nxtB = p; }
    if ((t >> bit) & 1) {
      mm(kA, curB, nxtA, nxtB);                               // K * cur
      { short* p;
        p = curA; curA = nxtA; nxtA = p;
        p = curB; curB = nxtB; nxtB = p; }
    }
  }

  short* kt = ws + KTAB + t * KSLOT;
  for (int s = tid; s < 960; s += 1024) {
    int f = s >> 6, ln = s & 63;            // f = kk*5 + nt
    int kk = f / 5, nt = f % 5;
    int k0 = kk * 32 + (ln >> 4) * 8;
    int n  = nt * 16 + (ln & 15);
    bf16x8 h8 = {}, l8 = {};
    if (k0 < 80) {
      const short* ap = curA + n * FROW + k0;
      h8 = *(const bf16x8*)ap;
      l8 = *(const bf16x8*)(ap + 96);
    }
    *(bf16x8*)(kt + f * 512 + ln * 8) = h8;
    *(bf16x8*)(kt + 7680 + f * 512 + ln * 8) = l8;
  }
}

// ---------------------------------------------------------------------------
// ypred body (256 thr): block = (bc: 128 batch rows, one t). Wave w owns
// local M-tiles {2w, 2w+1}. A hi/lo frags load DIRECTLY from the y0 frag
// table; B-frags from the K^t table. t=0 blocks reconstruct y0 = hi + lo.
// T5 setprio around each 6-MFMA cluster (symmetric with mlp: matrix pipe is
// fed by whichever co-resident wave has a ready cluster).
// ---------------------------------------------------------------------------
static __device__ __forceinline__ void ypred_body(int g, const short* __restrict__ ws,
                                                  float* __restrict__ yp, int tid) {
  const int lane = tid & 63;
  const int w    = tid >> 6;           // 0..3
  const int m16  = lane & 15;
  const int kg   = lane >> 4;
  const int bc   = g & 31;
  const int t    = g >> 5;             // 0..63
  const long b0  = (long)bc * 128;
  const short* y0f = ws + Y0F;

  if (t == 0) {
    for (int i = tid; i < 10240; i += 256) {
      const int r = i / 80, c = i - (i / 80) * 80;
      const int gmt = bc * 8 + (r >> 4);
      const int idx = ((gmt * 3 + (c >> 5)) * 64 + ((c & 31) >> 3) * 16 + (r & 15)) * 8 + (c & 7);
      yp[(b0 + r) * YROW + c] = bf2f(y0f[idx]) + bf2f(y0f[HPLANE + idx]);
    }
    return;
  }

  bf16x8 ah[2][3], al[2][3];
#pragma unroll
  for (int m = 0; m < 2; ++m) {
    const int gmt = bc * 8 + 2 * w + m;
#pragma unroll
    for (int kk = 0; kk < 3; ++kk) {
      const int idx = ((gmt * 3 + kk) * 64 + lane) * 8;
      ah[m][kk] = *(const bf16x8*)(y0f + idx);
      al[m][kk] = *(const bf16x8*)(y0f + HPLANE + idx);
    }
  }

  const short* kt = ws + KTAB + t * KSLOT;
  f32x4 acc[2][5];
#pragma unroll
  for (int m = 0; m < 2; ++m)
#pragma unroll
    for (int nt = 0; nt < 5; ++nt) acc[m][nt] = (f32x4){0.f, 0.f, 0.f, 0.f};

#pragma unroll
  for (int kk = 0; kk < 3; ++kk) {
#pragma unroll
    for (int nt = 0; nt < 5; ++nt) {
      const bf16x8 bh = *(const bf16x8*)(kt + ((kk * 5 + nt) * 64 + lane) * 8);
      const bf16x8 bl = *(const bf16x8*)(kt + 7680 + ((kk * 5 + nt) * 64 + lane) * 8);
      __builtin_amdgcn_s_setprio(1);
#pragma unroll
      for (int m = 0; m < 2; ++m) {
        acc[m][nt] = MFMA(ah[m][kk], bh, acc[m][nt], 0, 0, 0);
        acc[m][nt] = MFMA(al[m][kk], bh, acc[m][nt], 0, 0, 0);
        acc[m][nt] = MFMA(ah[m][kk], bl, acc[m][nt], 0, 0, 0);
      }
      __builtin_amdgcn_s_setprio(0);
    }
  }
#pragma unroll
  for (int m = 0; m < 2; ++m)
#pragma unroll
    for (int nt = 0; nt < 5; ++nt)
#pragma unroll
      for (int r = 0; r < 4; ++r)
        yp[(b0 + (2 * w + m) * 16 + kg * 4 + r) * YROW + (long)t * 80 + nt * 16 + m16] =
            acc[m][nt][r];
}

// ---------------------------------------------------------------------------
// Fused kernel (round-11 proven): 6144 blocks. bid%3==2 -> ypred block
// (write-BW bound), else -> mlp block (latency bound); interleave co-resides
// them per CU so ypred's HBM writes hide under mlp's stalls.
// ---------------------------------------------------------------------------
__global__ __launch_bounds__(256, 4) void fused_kernel(const float* __restrict__ x,
                                                       const float* __restrict__ b1g,
                                                       const float* __restrict__ b2g,
                                                       const short* __restrict__ ws,
                                                       float* __restrict__ y,
                                                       float* __restrict__ yp) {
  extern __shared__ char smem[];
  const int bid = blockIdx.x;
  const int g = bid / 3;
  const int r = bid - 3 * g;
  if (r == 2) {
    ypred_body(g, ws, yp, threadIdx.x);
  } else {
    mlp_body<16, 0>((long)(g * 2 + r), x, b1g, b2g, ws, y, nullptr,
                    (short*)smem, threadIdx.x);
  }
}

extern "C" void kernel_launch(void* const* d_in, const int* in_sizes, int n_in,
                              void* d_out, int out_size, void* d_ws, size_t ws_size,
                              hipStream_t stream) {
  const float* x  = (const float*)d_in[0];
  const float* W1 = (const float*)d_in[1];
  const float* b1 = (const float*)d_in[2];
  const float* W2 = (const float*)d_in[3];
  const float* b2 = (const float*)d_in[4];
  const float* W3 = (const float*)d_in[5];
  const float* Kg = (const float*)d_in[6];
  float* y  = (float*)d_out;
  float* yp = y + (long)NB * YROW;
  short* ws = (short*)d_ws;

  prep_kernel<<<256, 256, 0, stream>>>(W1, W2, W3, ws);
  kpow_mlp0_kernel<<<79, 1024, 5 * FIMG_B, stream>>>(Kg, x, b1, b2, ws);
  fused_kernel<<<6144, 256, HBYTES, stream>>>(x, b1, b2, ws, y, yp);
}

// Round 18
// 101.021 us; speedup vs baseline: 1.0026x; 1.0026x over previous
//
#include <hip/hip_runtime.h>
#include <hip/hip_bf16.h>

// Problem constants (hardcoded from setup_inputs; n_shifts == T == 64)
#define NB   4096
#define NT   64
#define NDIM 16
#define NH1  256
#define NH2  256
#define NLAT 64
#define NKD  80
#define YROW (NT * NKD)      // 5120 floats per batch row of y / y_pred
#define KTAB 98304           // short-offset of K-power fragment table in ws
#define KSLOT 15360          // shorts per t-slot (7680 hi + 7680 lo)
#define Y0F   1081344        // short-offset of y0 A-frag table
#define HPLANE 393216        // shorts per plane: 256 mtiles x 3 kk x 64 lane x 8 e

// h LDS row stride: 264 shorts = 528 B, 16B-aligned (round-14 lesson: 268
// broke b128 alignment, 1.5x slowdown). Residual 6.3M bank-conflict counter
// is 2-way-per-phase aliasing = absorbed slack (round-14 A/B).
#define HROW 264
#define HBYTES (64 * HROW * 2)   // 33792 B per 64-token h tile

// kpow frag-image geometry: hi at [row][0..79], lo at [row][96..175]
#define FROW 184
#define FIMG_B (80 * FROW * 2)   // 29440 bytes per image

typedef __attribute__((ext_vector_type(8))) short bf16x8;
typedef __attribute__((ext_vector_type(4))) float f32x4;

#define MFMA __builtin_amdgcn_mfma_f32_16x16x32_bf16

static __device__ __forceinline__ short f2bf(float f) {
  __hip_bfloat16 b = __float2bfloat16(f);      // native RNE cast (m240)
  return __builtin_bit_cast(short, b);
}
static __device__ __forceinline__ float bf2f(short h) {
  union { unsigned u; float f; } v; v.u = ((unsigned)(unsigned short)h) << 16;
  return v.f;
}
static __device__ __forceinline__ bf16x8 pack8(float4 a, float4 b) {
  bf16x8 r;
  r[0] = f2bf(a.x); r[1] = f2bf(a.y); r[2] = f2bf(a.z); r[3] = f2bf(a.w);
  r[4] = f2bf(b.x); r[5] = f2bf(b.y); r[6] = f2bf(b.z); r[7] = f2bf(b.w);
  return r;
}

// ---------------------------------------------------------------------------
// Prep: MFMA fragment order (bf16) for 16x16x32.
// Fragment: lane l holds W[g][k] with g = l&15, k = 8*(l>>4)+e.
// ws (shorts): [0) W2f 65536 | [65536) W3f 16384 | [81920) W1f 8192
// ---------------------------------------------------------------------------
__global__ __launch_bounds__(256) void prep_kernel(const float* __restrict__ W1,
                                                   const float* __restrict__ W2,
                                                   const float* __restrict__ W3,
                                                   short* __restrict__ ws) {
  int i = blockIdx.x * 256 + threadIdx.x;   // 0..65535
  {
    int e = i & 7, l = (i >> 3) & 63, nt = (i >> 9) & 15, kk = i >> 13;
    int g = nt * 16 + (l & 15);
    int h = kk * 32 + (l >> 4) * 8 + e;
    ws[i] = f2bf(W2[g * NH1 + h]);
  }
  if (i < 16384) {
    int e = i & 7, l = (i >> 3) & 63, nt = (i >> 9) & 3, kk = i >> 11;
    int g = nt * 16 + (l & 15);
    int h = kk * 32 + (l >> 4) * 8 + e;
    ws[65536 + i] = f2bf(W3[g * NH2 + h]);
  }
  if (i < 8192) {
    int e = i & 7, l = (i >> 3) & 63, nt = i >> 9;
    int g = nt * 16 + (l & 15);
    int k = (l >> 4) * 8 + e;
    ws[81920 + i] = (k < NDIM) ? f2bf(W1[g * NDIM + k]) : (short)0;
  }
}

// ---------------------------------------------------------------------------
// MLP body (round-16 proven: T5 setprio around GEMM2/GEMM3 MFMA clusters
// only — r17 showed extending it to GEMM1/ypred is null).
// MODE 0: write y rows; the x-part store is issued at the TOP (depends only
// on xv) so the copy writes drain under compute instead of the epilogue.
// MODE 1 (mlp0): write y0 hi/lo A-frag table at ws[Y0F].
// tid is TEAM-LOCAL (0..255); h1s is the team's private HBYTES LDS carve.
// ---------------------------------------------------------------------------
template <int XSTRIDE, int MODE>
static __device__ __forceinline__ void mlp_body(long b, const float* __restrict__ x,
                                                const float* __restrict__ b1g,
                                                const float* __restrict__ b2g,
                                                const short* __restrict__ ws,
                                                float* __restrict__ yo,
                                                short* __restrict__ y0f,
                                                short* h1s, int tid) {
  const int lane = tid & 63;
  const int w    = tid >> 6;            // 0..3
  const int l15  = lane & 15;
  const int kg   = lane >> 4;

  const short* W2f = ws;
  const short* W3f = ws + 65536;
  const short* W1f = ws + 81920;

  const float4 xv =
      *(const float4*)(x + (b * 64 + (tid >> 2)) * XSTRIDE + (tid & 3) * 4);

  if (MODE == 0) {
    // y x-part issued early: fire-and-forget store drains under GEMM1/2/3.
    *(float4*)(yo + (b * 64 + (tid >> 2)) * 80 + (tid & 3) * 4) = xv;
  }

  // ---- x B-frags (x^T): lane holds x[tok][k0..k0+7], tok = col ----
  bf16x8 xf[4];
#pragma unroll
  for (int j = 0; j < 4; ++j) {
    const int tok = j * 16 + l15;
    bf16x8 f = {};
    if (kg < 2) {
      const float4* p = (const float4*)(x + (b * 64 + tok) * XSTRIDE + kg * 8);
      f = pack8(p[0], p[1]);
    }
    xf[j] = f;
  }

  // ---- GEMM1: D = W1 x x^T -> h1[tok][h] via packed b64 stores ----
#pragma unroll
  for (int i = 0; i < 4; ++i) {
    const int mt = w * 4 + i;
    const bf16x8 wa = *(const bf16x8*)(W1f + (mt * 64 + lane) * 8);
    const float4 bias = *(const float4*)(b1g + mt * 16 + kg * 4);
#pragma unroll
    for (int j = 0; j < 4; ++j) {
      f32x4 c = {0.f, 0.f, 0.f, 0.f};
      c = MFMA(wa, xf[j], c, 0, 0, 0);
      const int tok = j * 16 + l15;
      float v0 = c[0] + bias.x; v0 = v0 > 0.f ? v0 : 0.f;
      float v1 = c[1] + bias.y; v1 = v1 > 0.f ? v1 : 0.f;
      float v2 = c[2] + bias.z; v2 = v2 > 0.f ? v2 : 0.f;
      float v3 = c[3] + bias.w; v3 = v3 > 0.f ? v3 : 0.f;
      short4 st = {f2bf(v0), f2bf(v1), f2bf(v2), f2bf(v3)};
      *(short4*)(h1s + tok * HROW + mt * 16 + kg * 4) = st;
    }
  }
  __syncthreads();

  // ---- GEMM2: D = W2 x h1^T; K=256; acc 4mt x 4nt ----
  f32x4 acc2[4][4];
#pragma unroll
  for (int i = 0; i < 4; ++i)
#pragma unroll
    for (int j = 0; j < 4; ++j) acc2[i][j] = (f32x4){0.f, 0.f, 0.f, 0.f};

#pragma unroll 2
  for (int kk = 0; kk < 8; ++kk) {
    bf16x8 wa[4], hb[4];
#pragma unroll
    for (int i = 0; i < 4; ++i)
      wa[i] = *(const bf16x8*)(W2f + ((kk * 16 + w * 4 + i) * 64 + lane) * 8);
#pragma unroll
    for (int j = 0; j < 4; ++j)
      hb[j] = *(const bf16x8*)(h1s + (j * 16 + l15) * HROW + kk * 32 + kg * 8);
    __builtin_amdgcn_s_setprio(1);
#pragma unroll
    for (int i = 0; i < 4; ++i)
#pragma unroll
      for (int j = 0; j < 4; ++j)
        acc2[i][j] = MFMA(wa[i], hb[j], acc2[i][j], 0, 0, 0);
    __builtin_amdgcn_s_setprio(0);
  }
  __syncthreads();   // all h1 reads done -> overlay h2

#pragma unroll
  for (int i = 0; i < 4; ++i) {
    const int mt = w * 4 + i;
    const float4 bias = *(const float4*)(b2g + mt * 16 + kg * 4);
#pragma unroll
    for (int j = 0; j < 4; ++j) {
      const int tok = j * 16 + l15;
      float v0 = acc2[i][j][0] + bias.x; v0 = v0 > 0.f ? v0 : 0.f;
      float v1 = acc2[i][j][1] + bias.y; v1 = v1 > 0.f ? v1 : 0.f;
      float v2 = acc2[i][j][2] + bias.z; v2 = v2 > 0.f ? v2 : 0.f;
      float v3 = acc2[i][j][3] + bias.w; v3 = v3 > 0.f ? v3 : 0.f;
      short4 st = {f2bf(v0), f2bf(v1), f2bf(v2), f2bf(v3)};
      *(short4*)(h1s + tok * HROW + mt * 16 + kg * 4) = st;
    }
  }
  __syncthreads();

  // ---- GEMM3: D = W3 x h2^T ----
  f32x4 acc3[4];
#pragma unroll
  for (int j = 0; j < 4; ++j) acc3[j] = (f32x4){0.f, 0.f, 0.f, 0.f};
#pragma unroll 2
  for (int kk = 0; kk < 8; ++kk) {
    const bf16x8 wa = *(const bf16x8*)(W3f + ((kk * 4 + w) * 64 + lane) * 8);
    bf16x8 hb[4];
#pragma unroll
    for (int j = 0; j < 4; ++j)
      hb[j] = *(const bf16x8*)(h1s + (j * 16 + l15) * HROW + kk * 32 + kg * 8);
    __builtin_amdgcn_s_setprio(1);
#pragma unroll
    for (int j = 0; j < 4; ++j)
      acc3[j] = MFMA(wa, hb[j], acc3[j], 0, 0, 0);
    __builtin_amdgcn_s_setprio(0);
  }

  if (MODE == 0) {
    // y g-part (one float4 per tile); x-part was stored at the top
#pragma unroll
    for (int j = 0; j < 4; ++j) {
      const int tok = j * 16 + l15;
      *(float4*)(yo + (b * 64 + tok) * 80 + 16 + w * 16 + kg * 4) =
          *(float4*)&acc3[j];
    }
  } else {
    // ---- y0 hi/lo A-frag table epilogue ----
    {
      const int t0 = tid >> 2;
      const int gmt = (int)b * 4 + (t0 >> 4);
      const int c0x = (tid & 3) * 4;
      const int lanef = (c0x >> 3) * 16 + (t0 & 15);
      short h0 = f2bf(xv.x), h1 = f2bf(xv.y), h2 = f2bf(xv.z), h3 = f2bf(xv.w);
      short4 hs = {h0, h1, h2, h3};
      short4 ls = {f2bf(xv.x - bf2f(h0)), f2bf(xv.y - bf2f(h1)),
                   f2bf(xv.z - bf2f(h2)), f2bf(xv.w - bf2f(h3))};
      const int idx = ((gmt * 3 + 0) * 64 + lanef) * 8 + (c0x & 7);
      *(short4*)(y0f + idx) = hs;
      *(short4*)(y0f + HPLANE + idx) = ls;
    }
    const int c0 = 16 + w * 16 + kg * 4;
    const int kkf = c0 >> 5;
    const int lanef = ((c0 & 31) >> 3) * 16 + l15;
#pragma unroll
    for (int j = 0; j < 4; ++j) {
      const int gmt = (int)b * 4 + j;
      short h0 = f2bf(acc3[j][0]), h1 = f2bf(acc3[j][1]);
      short h2 = f2bf(acc3[j][2]), h3 = f2bf(acc3[j][3]);
      short4 hs = {h0, h1, h2, h3};
      short4 ls = {f2bf(acc3[j][0] - bf2f(h0)), f2bf(acc3[j][1] - bf2f(h1)),
                   f2bf(acc3[j][2] - bf2f(h2)), f2bf(acc3[j][3] - bf2f(h3))};
      const int idx = ((gmt * 3 + kkf) * 64 + lanef) * 8 + (c0 & 7);
      *(short4*)(y0f + idx) = hs;
      *(short4*)(y0f + HPLANE + idx) = ls;
    }
    // zero-fill k in [80,96): kk=2, lanes 32..63 (ws is poisoned, not zeroed)
    {
      const int plane = tid & 1;
      const int lz = 32 + ((tid >> 1) & 31);
      const int gmt = (int)b * 4 + (tid >> 6);
      bf16x8 z = {};
      *(bf16x8*)(y0f + plane * HPLANE + ((gmt * 3 + 2) * 64 + lz) * 8) = z;
    }
  }
}

// ---------------------------------------------------------------------------
// kpow+mlp0 fused launch (79 blocks x 1024 threads, 147200 B LDS):
//   bid 0..62 -> kpow: K^(bid+1), 16 waves (mm tiles id += 16).
//   bid 63..78 -> mlp0 x4: four independent 256-thr teams per block, each
//               running the token-0 MLP for 64 batch rows with a private
//               HBYTES h1s carve (4 x 33792 = 135168 <= 147200).
// ---------------------------------------------------------------------------
__global__ __launch_bounds__(1024, 4) void kpow_mlp0_kernel(const float* __restrict__ Kg,
                                                            const float* __restrict__ x,
                                                            const float* __restrict__ b1g,
                                                            const float* __restrict__ b2g,
                                                            short* __restrict__ ws) {
  extern __shared__ char smem[];
  const int tid = threadIdx.x;

  if (blockIdx.x >= 63) {
    const int team = tid >> 8;           // 0..3
    const int ttid = tid & 255;
    const long b = (long)(blockIdx.x - 63) * 4 + team;   // 0..63
    mlp_body<1024, 1>(b, x, b1g, b2g, ws, nullptr, ws + Y0F,
                      (short*)(smem + team * HBYTES), ttid);
    return;
  }

  short* kA   = (short*)smem;
  short* curA = (short*)(smem + FIMG_B);
  short* curB = (short*)(smem + 2 * FIMG_B);
  short* nxtA = (short*)(smem + 3 * FIMG_B);
  short* nxtB = (short*)(smem + 4 * FIMG_B);

  const int lane = tid & 63;
  const int w    = tid >> 6;            // 0..15
  const int l15  = lane & 15;
  const int kg   = lane >> 4;
  const int t    = blockIdx.x + 1;      // 1..63

  for (int i = tid; i < 6400; i += 1024) {
    float v = Kg[i];
    int r = i / 80, c = i - r * 80;
    short hi = f2bf(v);
    short lo = f2bf(v - bf2f(hi));
    kA[r * FROW + c] = hi;        kA[r * FROW + 96 + c] = lo;
    curA[r * FROW + c] = hi;      curA[r * FROW + 96 + c] = lo;
    curB[c * FROW + r] = hi;      curB[c * FROW + 96 + r] = lo;
  }
  __syncthreads();

  auto mm = [&](const short* Ai, const short* Bi, short* DA, short* DB) {
    for (int id = w; id < 25; id += 16) {
      const int mt = id / 5, nt = id % 5;
      f32x4 acc = {0.f, 0.f, 0.f, 0.f};
#pragma unroll
      for (int kk = 0; kk < 3; ++kk) {
        const int k0 = kk * 32 + kg * 8;
        bf16x8 ah = {}, al = {}, bh = {}, bl = {};
        if (k0 < 80) {
          const short* ap = Ai + (mt * 16 + l15) * FROW + k0;
          const short* bp = Bi + (nt * 16 + l15) * FROW + k0;
          ah = *(const bf16x8*)ap;  al = *(const bf16x8*)(ap + 96);
          bh = *(const bf16x8*)bp;  bl = *(const bf16x8*)(bp + 96);
        }
        acc = MFMA(ah, bh, acc, 0, 0, 0);
        acc = MFMA(al, bh, acc, 0, 0, 0);
        acc = MFMA(ah, bl, acc, 0, 0, 0);
      }
      const int n = nt * 16 + l15;
      const int rowb = mt * 16 + kg * 4;
      short4 hs, ls;
#pragma unroll
      for (int r = 0; r < 4; ++r) {
        float v = acc[r];
        short hi = f2bf(v);
        short lo = f2bf(v - bf2f(hi));
        DA[(rowb + r) * FROW + n] = hi;
        DA[(rowb + r) * FROW + 96 + n] = lo;
        ((short*)&hs)[r] = hi;
        ((short*)&ls)[r] = lo;
      }
      *(short4*)(DB + n * FROW + rowb) = hs;
      *(short4*)(DB + n * FROW + 96 + rowb) = ls;
    }
    __syncthreads();
  };

  const int h = 31 - __clz(t);
  for (int bit = h - 1; bit >= 0; --bit) {
    mm(curA, curB, nxtA, nxtB);                               // square
    { short* p;
      p = curA; curA = nxtA; nxtA = p;
      p = curB; curB = nxtB; nxtB = p; }
    if ((t >> bit) & 1) {
      mm(kA, curB, nxtA, nxtB);                               // K * cur
      { short* p;
        p = curA; curA = nxtA; nxtA = p;
        p = curB; curB = nxtB; nxtB = p; }
    }
  }

  short* kt = ws + KTAB + t * KSLOT;
  for (int s = tid; s < 960; s += 1024) {
    int f = s >> 6, ln = s & 63;            // f = kk*5 + nt
    int kk = f / 5, nt = f % 5;
    int k0 = kk * 32 + (ln >> 4) * 8;
    int n  = nt * 16 + (ln & 15);
    bf16x8 h8 = {}, l8 = {};
    if (k0 < 80) {
      const short* ap = curA + n * FROW + k0;
      h8 = *(const bf16x8*)ap;
      l8 = *(const bf16x8*)(ap + 96);
    }
    *(bf16x8*)(kt + f * 512 + ln * 8) = h8;
    *(bf16x8*)(kt + 7680 + f * 512 + ln * 8) = l8;
  }
}

// ---------------------------------------------------------------------------
// ypred body (256 thr, round-16 version — no setprio, r17 null): block =
// (bc: 128 batch rows, one t). Wave w owns local M-tiles {2w, 2w+1}. A hi/lo
// frags load DIRECTLY from the y0 frag table; B-frags from the K^t table.
// t=0 blocks reconstruct y0 = hi + lo.
// ---------------------------------------------------------------------------
static __device__ __forceinline__ void ypred_body(int g, const short* __restrict__ ws,
                                                  float* __restrict__ yp, int tid) {
  const int lane = tid & 63;
  const int w    = tid >> 6;           // 0..3
  const int m16  = lane & 15;
  const int kg   = lane >> 4;
  const int bc   = g & 31;
  const int t    = g >> 5;             // 0..63
  const long b0  = (long)bc * 128;
  const short* y0f = ws + Y0F;

  if (t == 0) {
    for (int i = tid; i < 10240; i += 256) {
      const int r = i / 80, c = i - (i / 80) * 80;
      const int gmt = bc * 8 + (r >> 4);
      const int idx = ((gmt * 3 + (c >> 5)) * 64 + ((c & 31) >> 3) * 16 + (r & 15)) * 8 + (c & 7);
      yp[(b0 + r) * YROW + c] = bf2f(y0f[idx]) + bf2f(y0f[HPLANE + idx]);
    }
    return;
  }

  bf16x8 ah[2][3], al[2][3];
#pragma unroll
  for (int m = 0; m < 2; ++m) {
    const int gmt = bc * 8 + 2 * w + m;
#pragma unroll
    for (int kk = 0; kk < 3; ++kk) {
      const int idx = ((gmt * 3 + kk) * 64 + lane) * 8;
      ah[m][kk] = *(const bf16x8*)(y0f + idx);
      al[m][kk] = *(const bf16x8*)(y0f + HPLANE + idx);
    }
  }

  const short* kt = ws + KTAB + t * KSLOT;
  f32x4 acc[2][5];
#pragma unroll
  for (int m = 0; m < 2; ++m)
#pragma unroll
    for (int nt = 0; nt < 5; ++nt) acc[m][nt] = (f32x4){0.f, 0.f, 0.f, 0.f};

#pragma unroll
  for (int kk = 0; kk < 3; ++kk) {
#pragma unroll
    for (int nt = 0; nt < 5; ++nt) {
      const bf16x8 bh = *(const bf16x8*)(kt + ((kk * 5 + nt) * 64 + lane) * 8);
      const bf16x8 bl = *(const bf16x8*)(kt + 7680 + ((kk * 5 + nt) * 64 + lane) * 8);
#pragma unroll
      for (int m = 0; m < 2; ++m) {
        acc[m][nt] = MFMA(ah[m][kk], bh, acc[m][nt], 0, 0, 0);
        acc[m][nt] = MFMA(al[m][kk], bh, acc[m][nt], 0, 0, 0);
        acc[m][nt] = MFMA(ah[m][kk], bl, acc[m][nt], 0, 0, 0);
      }
    }
  }
#pragma unroll
  for (int m = 0; m < 2; ++m)
#pragma unroll
    for (int nt = 0; nt < 5; ++nt)
#pragma unroll
      for (int r = 0; r < 4; ++r)
        yp[(b0 + (2 * w + m) * 16 + kg * 4 + r) * YROW + (long)t * 80 + nt * 16 + m16] =
            acc[m][nt][r];
}

// ---------------------------------------------------------------------------
// Fused kernel (round-11 proven): 6144 blocks. bid%3==2 -> ypred block
// (write-BW bound), else -> mlp block (latency bound); interleave co-resides
// them per CU so ypred's HBM writes hide under mlp's stalls.
// ---------------------------------------------------------------------------
__global__ __launch_bounds__(256, 4) void fused_kernel(const float* __restrict__ x,
                                                       const float* __restrict__ b1g,
                                                       const float* __restrict__ b2g,
                                                       const short* __restrict__ ws,
                                                       float* __restrict__ y,
                                                       float* __restrict__ yp) {
  extern __shared__ char smem[];
  const int bid = blockIdx.x;
  const int g = bid / 3;
  const int r = bid - 3 * g;
  if (r == 2) {
    ypred_body(g, ws, yp, threadIdx.x);
  } else {
    mlp_body<16, 0>((long)(g * 2 + r), x, b1g, b2g, ws, y, nullptr,
                    (short*)smem, threadIdx.x);
  }
}

extern "C" void kernel_launch(void* const* d_in, const int* in_sizes, int n_in,
                              void* d_out, int out_size, void* d_ws, size_t ws_size,
                              hipStream_t stream) {
  const float* x  = (const float*)d_in[0];
  const float* W1 = (const float*)d_in[1];
  const float* b1 = (const float*)d_in[2];
  const float* W2 = (const float*)d_in[3];
  const float* b2 = (const float*)d_in[4];
  const float* W3 = (const float*)d_in[5];
  const float* Kg = (const float*)d_in[6];
  float* y  = (float*)d_out;
  float* yp = y + (long)NB * YROW;
  short* ws = (short*)d_ws;

  prep_kernel<<<256, 256, 0, stream>>>(W1, W2, W3, ws);
  kpow_mlp0_kernel<<<79, 1024, 5 * FIMG_B, stream>>>(Kg, x, b1, b2, ws);
  fused_kernel<<<6144, 256, HBYTES, stream>>>(x, b1, b2, ws, y, yp);
}

// Round 19
// 100.638 us; speedup vs baseline: 1.0064x; 1.0038x over previous
//
#include <hip/hip_runtime.h>
#include <hip/hip_bf16.h>

// Problem constants (hardcoded from setup_inputs; n_shifts == T == 64)
#define NB   4096
#define NT   64
#define NDIM 16
#define NH1  256
#define NH2  256
#define NLAT 64
#define NKD  80
#define YROW (NT * NKD)      // 5120 floats per batch row of y / y_pred
#define KTAB 98304           // short-offset of K-power fragment table in ws
#define KSLOT 15360          // shorts per t-slot (7680 hi + 7680 lo)
#define Y0F   1081344        // short-offset of y0 A-frag table
#define HPLANE 393216        // shorts per plane: 256 mtiles x 3 kk x 64 lane x 8 e

// h tile: [64 tok][256 units] bf16 = 32768 B -> 5 blocks/CU (5 x 32768 =
// 163840 = exactly 160 KiB), 20 waves/CU vs 16 at the old 33792-B tile.
// Stride 256 shorts == 0 mod 32 banks would be 16-way conflicted, so unit
// index is XOR-swizzled with (tok&7)<<3 (T2): flips bits 3-5 only ->
// preserves the 8-short read / 4-short write granule alignment; writers and
// readers apply the same involution (both-sides rule).
#define HROW 256
#define HBYTES (64 * HROW * 2)   // 32768 B per 64-token h tile

static __device__ __forceinline__ int hoff(int tok, int unit) {
  return tok * HROW + (unit ^ ((tok & 7) << 3));
}

// kpow frag-image geometry: hi at [row][0..79], lo at [row][96..175]
#define FROW 184
#define FIMG_B (80 * FROW * 2)   // 29440 bytes per image

typedef __attribute__((ext_vector_type(8))) short bf16x8;
typedef __attribute__((ext_vector_type(4))) float f32x4;

#define MFMA __builtin_amdgcn_mfma_f32_16x16x32_bf16

static __device__ __forceinline__ short f2bf(float f) {
  __hip_bfloat16 b = __float2bfloat16(f);      // native RNE cast (m240)
  return __builtin_bit_cast(short, b);
}
static __device__ __forceinline__ float bf2f(short h) {
  union { unsigned u; float f; } v; v.u = ((unsigned)(unsigned short)h) << 16;
  return v.f;
}
static __device__ __forceinline__ bf16x8 pack8(float4 a, float4 b) {
  bf16x8 r;
  r[0] = f2bf(a.x); r[1] = f2bf(a.y); r[2] = f2bf(a.z); r[3] = f2bf(a.w);
  r[4] = f2bf(b.x); r[5] = f2bf(b.y); r[6] = f2bf(b.z); r[7] = f2bf(b.w);
  return r;
}

// ---------------------------------------------------------------------------
// Prep: MFMA fragment order (bf16) for 16x16x32.
// Fragment: lane l holds W[g][k] with g = l&15, k = 8*(l>>4)+e.
// ws (shorts): [0) W2f 65536 | [65536) W3f 16384 | [81920) W1f 8192
// ---------------------------------------------------------------------------
__global__ __launch_bounds__(256) void prep_kernel(const float* __restrict__ W1,
                                                   const float* __restrict__ W2,
                                                   const float* __restrict__ W3,
                                                   short* __restrict__ ws) {
  int i = blockIdx.x * 256 + threadIdx.x;   // 0..65535
  {
    int e = i & 7, l = (i >> 3) & 63, nt = (i >> 9) & 15, kk = i >> 13;
    int g = nt * 16 + (l & 15);
    int h = kk * 32 + (l >> 4) * 8 + e;
    ws[i] = f2bf(W2[g * NH1 + h]);
  }
  if (i < 16384) {
    int e = i & 7, l = (i >> 3) & 63, nt = (i >> 9) & 3, kk = i >> 11;
    int g = nt * 16 + (l & 15);
    int h = kk * 32 + (l >> 4) * 8 + e;
    ws[65536 + i] = f2bf(W3[g * NH2 + h]);
  }
  if (i < 8192) {
    int e = i & 7, l = (i >> 3) & 63, nt = i >> 9;
    int g = nt * 16 + (l & 15);
    int k = (l >> 4) * 8 + e;
    ws[81920 + i] = (k < NDIM) ? f2bf(W1[g * NDIM + k]) : (short)0;
  }
}

// ---------------------------------------------------------------------------
// MLP body (round-16 proven: T5 setprio around GEMM2/GEMM3 MFMA clusters
// only). h tile accesses go through hoff() (XOR-swizzled 256-unit rows).
// MODE 0: write y rows. MODE 1 (mlp0): write y0 hi/lo A-frag table at ws[Y0F].
// tid is TEAM-LOCAL (0..255); h1s is the team's private HBYTES LDS carve.
// ---------------------------------------------------------------------------
template <int XSTRIDE, int MODE>
static __device__ __forceinline__ void mlp_body(long b, const float* __restrict__ x,
                                                const float* __restrict__ b1g,
                                                const float* __restrict__ b2g,
                                                const short* __restrict__ ws,
                                                float* __restrict__ yo,
                                                short* __restrict__ y0f,
                                                short* h1s, int tid) {
  const int lane = tid & 63;
  const int w    = tid >> 6;            // 0..3
  const int l15  = lane & 15;
  const int kg   = lane >> 4;

  const short* W2f = ws;
  const short* W3f = ws + 65536;
  const short* W1f = ws + 81920;

  const float4 xv =
      *(const float4*)(x + (b * 64 + (tid >> 2)) * XSTRIDE + (tid & 3) * 4);

  // ---- x B-frags (x^T): lane holds x[tok][k0..k0+7], tok = col ----
  bf16x8 xf[4];
#pragma unroll
  for (int j = 0; j < 4; ++j) {
    const int tok = j * 16 + l15;
    bf16x8 f = {};
    if (kg < 2) {
      const float4* p = (const float4*)(x + (b * 64 + tok) * XSTRIDE + kg * 8);
      f = pack8(p[0], p[1]);
    }
    xf[j] = f;
  }

  // ---- GEMM1: D = W1 x x^T -> h1[tok][h] via packed b64 stores ----
#pragma unroll
  for (int i = 0; i < 4; ++i) {
    const int mt = w * 4 + i;
    const bf16x8 wa = *(const bf16x8*)(W1f + (mt * 64 + lane) * 8);
    const float4 bias = *(const float4*)(b1g + mt * 16 + kg * 4);
#pragma unroll
    for (int j = 0; j < 4; ++j) {
      f32x4 c = {0.f, 0.f, 0.f, 0.f};
      c = MFMA(wa, xf[j], c, 0, 0, 0);
      const int tok = j * 16 + l15;
      float v0 = c[0] + bias.x; v0 = v0 > 0.f ? v0 : 0.f;
      float v1 = c[1] + bias.y; v1 = v1 > 0.f ? v1 : 0.f;
      float v2 = c[2] + bias.z; v2 = v2 > 0.f ? v2 : 0.f;
      float v3 = c[3] + bias.w; v3 = v3 > 0.f ? v3 : 0.f;
      short4 st = {f2bf(v0), f2bf(v1), f2bf(v2), f2bf(v3)};
      *(short4*)(h1s + hoff(tok, mt * 16 + kg * 4)) = st;
    }
  }
  __syncthreads();

  // ---- GEMM2: D = W2 x h1^T; K=256; acc 4mt x 4nt ----
  f32x4 acc2[4][4];
#pragma unroll
  for (int i = 0; i < 4; ++i)
#pragma unroll
    for (int j = 0; j < 4; ++j) acc2[i][j] = (f32x4){0.f, 0.f, 0.f, 0.f};

#pragma unroll 2
  for (int kk = 0; kk < 8; ++kk) {
    bf16x8 wa[4], hb[4];
#pragma unroll
    for (int i = 0; i < 4; ++i)
      wa[i] = *(const bf16x8*)(W2f + ((kk * 16 + w * 4 + i) * 64 + lane) * 8);
#pragma unroll
    for (int j = 0; j < 4; ++j)
      hb[j] = *(const bf16x8*)(h1s + hoff(j * 16 + l15, kk * 32 + kg * 8));
    __builtin_amdgcn_s_setprio(1);
#pragma unroll
    for (int i = 0; i < 4; ++i)
#pragma unroll
      for (int j = 0; j < 4; ++j)
        acc2[i][j] = MFMA(wa[i], hb[j], acc2[i][j], 0, 0, 0);
    __builtin_amdgcn_s_setprio(0);
  }
  __syncthreads();   // all h1 reads done -> overlay h2

#pragma unroll
  for (int i = 0; i < 4; ++i) {
    const int mt = w * 4 + i;
    const float4 bias = *(const float4*)(b2g + mt * 16 + kg * 4);
#pragma unroll
    for (int j = 0; j < 4; ++j) {
      const int tok = j * 16 + l15;
      float v0 = acc2[i][j][0] + bias.x; v0 = v0 > 0.f ? v0 : 0.f;
      float v1 = acc2[i][j][1] + bias.y; v1 = v1 > 0.f ? v1 : 0.f;
      float v2 = acc2[i][j][2] + bias.z; v2 = v2 > 0.f ? v2 : 0.f;
      float v3 = acc2[i][j][3] + bias.w; v3 = v3 > 0.f ? v3 : 0.f;
      short4 st = {f2bf(v0), f2bf(v1), f2bf(v2), f2bf(v3)};
      *(short4*)(h1s + hoff(tok, mt * 16 + kg * 4)) = st;
    }
  }
  __syncthreads();

  // ---- GEMM3: D = W3 x h2^T ----
  f32x4 acc3[4];
#pragma unroll
  for (int j = 0; j < 4; ++j) acc3[j] = (f32x4){0.f, 0.f, 0.f, 0.f};
#pragma unroll 2
  for (int kk = 0; kk < 8; ++kk) {
    const bf16x8 wa = *(const bf16x8*)(W3f + ((kk * 4 + w) * 64 + lane) * 8);
    bf16x8 hb[4];
#pragma unroll
    for (int j = 0; j < 4; ++j)
      hb[j] = *(const bf16x8*)(h1s + hoff(j * 16 + l15, kk * 32 + kg * 8));
    __builtin_amdgcn_s_setprio(1);
#pragma unroll
    for (int j = 0; j < 4; ++j)
      acc3[j] = MFMA(wa, hb[j], acc3[j], 0, 0, 0);
    __builtin_amdgcn_s_setprio(0);
  }

  if (MODE == 0) {
    // y x-part (exact f32 from regs) + g-part (one float4 per tile)
    *(float4*)(yo + (b * 64 + (tid >> 2)) * 80 + (tid & 3) * 4) = xv;
#pragma unroll
    for (int j = 0; j < 4; ++j) {
      const int tok = j * 16 + l15;
      *(float4*)(yo + (b * 64 + tok) * 80 + 16 + w * 16 + kg * 4) =
          *(float4*)&acc3[j];
    }
  } else {
    // ---- y0 hi/lo A-frag table epilogue ----
    {
      const int t0 = tid >> 2;
      const int gmt = (int)b * 4 + (t0 >> 4);
      const int c0x = (tid & 3) * 4;
      const int lanef = (c0x >> 3) * 16 + (t0 & 15);
      short h0 = f2bf(xv.x), h1 = f2bf(xv.y), h2 = f2bf(xv.z), h3 = f2bf(xv.w);
      short4 hs = {h0, h1, h2, h3};
      short4 ls = {f2bf(xv.x - bf2f(h0)), f2bf(xv.y - bf2f(h1)),
                   f2bf(xv.z - bf2f(h2)), f2bf(xv.w - bf2f(h3))};
      const int idx = ((gmt * 3 + 0) * 64 + lanef) * 8 + (c0x & 7);
      *(short4*)(y0f + idx) = hs;
      *(short4*)(y0f + HPLANE + idx) = ls;
    }
    const int c0 = 16 + w * 16 + kg * 4;
    const int kkf = c0 >> 5;
    const int lanef = ((c0 & 31) >> 3) * 16 + l15;
#pragma unroll
    for (int j = 0; j < 4; ++j) {
      const int gmt = (int)b * 4 + j;
      short h0 = f2bf(acc3[j][0]), h1 = f2bf(acc3[j][1]);
      short h2 = f2bf(acc3[j][2]), h3 = f2bf(acc3[j][3]);
      short4 hs = {h0, h1, h2, h3};
      short4 ls = {f2bf(acc3[j][0] - bf2f(h0)), f2bf(acc3[j][1] - bf2f(h1)),
                   f2bf(acc3[j][2] - bf2f(h2)), f2bf(acc3[j][3] - bf2f(h3))};
      const int idx = ((gmt * 3 + kkf) * 64 + lanef) * 8 + (c0 & 7);
      *(short4*)(y0f + idx) = hs;
      *(short4*)(y0f + HPLANE + idx) = ls;
    }
    // zero-fill k in [80,96): kk=2, lanes 32..63 (ws is poisoned, not zeroed)
    {
      const int plane = tid & 1;
      const int lz = 32 + ((tid >> 1) & 31);
      const int gmt = (int)b * 4 + (tid >> 6);
      bf16x8 z = {};
      *(bf16x8*)(y0f + plane * HPLANE + ((gmt * 3 + 2) * 64 + lz) * 8) = z;
    }
  }
}

// ---------------------------------------------------------------------------
// kpow+mlp0 fused launch (79 blocks x 1024 threads, 147200 B LDS):
//   bid 0..62 -> kpow: K^(bid+1), 16 waves (mm tiles id += 16).
//   bid 63..78 -> mlp0 x4: four independent 256-thr teams per block, each
//               running the token-0 MLP for 64 batch rows with a private
//               HBYTES h1s carve (4 x 32768 = 131072 <= 147200).
// ---------------------------------------------------------------------------
__global__ __launch_bounds__(1024, 4) void kpow_mlp0_kernel(const float* __restrict__ Kg,
                                                            const float* __restrict__ x,
                                                            const float* __restrict__ b1g,
                                                            const float* __restrict__ b2g,
                                                            short* __restrict__ ws) {
  extern __shared__ char smem[];
  const int tid = threadIdx.x;

  if (blockIdx.x >= 63) {
    const int team = tid >> 8;           // 0..3
    const int ttid = tid & 255;
    const long b = (long)(blockIdx.x - 63) * 4 + team;   // 0..63
    mlp_body<1024, 1>(b, x, b1g, b2g, ws, nullptr, ws + Y0F,
                      (short*)(smem + team * HBYTES), ttid);
    return;
  }

  short* kA   = (short*)smem;
  short* curA = (short*)(smem + FIMG_B);
  short* curB = (short*)(smem + 2 * FIMG_B);
  short* nxtA = (short*)(smem + 3 * FIMG_B);
  short* nxtB = (short*)(smem + 4 * FIMG_B);

  const int lane = tid & 63;
  const int w    = tid >> 6;            // 0..15
  const int l15  = lane & 15;
  const int kg   = lane >> 4;
  const int t    = blockIdx.x + 1;      // 1..63

  for (int i = tid; i < 6400; i += 1024) {
    float v = Kg[i];
    int r = i / 80, c = i - r * 80;
    short hi = f2bf(v);
    short lo = f2bf(v - bf2f(hi));
    kA[r * FROW + c] = hi;        kA[r * FROW + 96 + c] = lo;
    curA[r * FROW + c] = hi;      curA[r * FROW + 96 + c] = lo;
    curB[c * FROW + r] = hi;      curB[c * FROW + 96 + r] = lo;
  }
  __syncthreads();

  auto mm = [&](const short* Ai, const short* Bi, short* DA, short* DB) {
    for (int id = w; id < 25; id += 16) {
      const int mt = id / 5, nt = id % 5;
      f32x4 acc = {0.f, 0.f, 0.f, 0.f};
#pragma unroll
      for (int kk = 0; kk < 3; ++kk) {
        const int k0 = kk * 32 + kg * 8;
        bf16x8 ah = {}, al = {}, bh = {}, bl = {};
        if (k0 < 80) {
          const short* ap = Ai + (mt * 16 + l15) * FROW + k0;
          const short* bp = Bi + (nt * 16 + l15) * FROW + k0;
          ah = *(const bf16x8*)ap;  al = *(const bf16x8*)(ap + 96);
          bh = *(const bf16x8*)bp;  bl = *(const bf16x8*)(bp + 96);
        }
        acc = MFMA(ah, bh, acc, 0, 0, 0);
        acc = MFMA(al, bh, acc, 0, 0, 0);
        acc = MFMA(ah, bl, acc, 0, 0, 0);
      }
      const int n = nt * 16 + l15;
      const int rowb = mt * 16 + kg * 4;
      short4 hs, ls;
#pragma unroll
      for (int r = 0; r < 4; ++r) {
        float v = acc[r];
        short hi = f2bf(v);
        short lo = f2bf(v - bf2f(hi));
        DA[(rowb + r) * FROW + n] = hi;
        DA[(rowb + r) * FROW + 96 + n] = lo;
        ((short*)&hs)[r] = hi;
        ((short*)&ls)[r] = lo;
      }
      *(short4*)(DB + n * FROW + rowb) = hs;
      *(short4*)(DB + n * FROW + 96 + rowb) = ls;
    }
    __syncthreads();
  };

  const int h = 31 - __clz(t);
  for (int bit = h - 1; bit >= 0; --bit) {
    mm(curA, curB, nxtA, nxtB);                               // square
    { short* p;
      p = curA; curA = nxtA; nxtA = p;
      p = curB; curB = nxtB; nxtB = p; }
    if ((t >> bit) & 1) {
      mm(kA, curB, nxtA, nxtB);                               // K * cur
      { short* p;
        p = curA; curA = nxtA; nxtA = p;
        p = curB; curB = nxtB; nxtB = p; }
    }
  }

  short* kt = ws + KTAB + t * KSLOT;
  for (int s = tid; s < 960; s += 1024) {
    int f = s >> 6, ln = s & 63;            // f = kk*5 + nt
    int kk = f / 5, nt = f % 5;
    int k0 = kk * 32 + (ln >> 4) * 8;
    int n  = nt * 16 + (ln & 15);
    bf16x8 h8 = {}, l8 = {};
    if (k0 < 80) {
      const short* ap = curA + n * FROW + k0;
      h8 = *(const bf16x8*)ap;
      l8 = *(const bf16x8*)(ap + 96);
    }
    *(bf16x8*)(kt + f * 512 + ln * 8) = h8;
    *(bf16x8*)(kt + 7680 + f * 512 + ln * 8) = l8;
  }
}

// ---------------------------------------------------------------------------
// ypred body (256 thr, round-16 version): block = (bc: 128 batch rows, one
// t). Wave w owns local M-tiles {2w, 2w+1}. A hi/lo frags load DIRECTLY from
// the y0 frag table; B-frags from the K^t table. t=0 blocks reconstruct y0.
// ---------------------------------------------------------------------------
static __device__ __forceinline__ void ypred_body(int g, const short* __restrict__ ws,
                                                  float* __restrict__ yp, int tid) {
  const int lane = tid & 63;
  const int w    = tid >> 6;           // 0..3
  const int m16  = lane & 15;
  const int kg   = lane >> 4;
  const int bc   = g & 31;
  const int t    = g >> 5;             // 0..63
  const long b0  = (long)bc * 128;
  const short* y0f = ws + Y0F;

  if (t == 0) {
    for (int i = tid; i < 10240; i += 256) {
      const int r = i / 80, c = i - (i / 80) * 80;
      const int gmt = bc * 8 + (r >> 4);
      const int idx = ((gmt * 3 + (c >> 5)) * 64 + ((c & 31) >> 3) * 16 + (r & 15)) * 8 + (c & 7);
      yp[(b0 + r) * YROW + c] = bf2f(y0f[idx]) + bf2f(y0f[HPLANE + idx]);
    }
    return;
  }

  bf16x8 ah[2][3], al[2][3];
#pragma unroll
  for (int m = 0; m < 2; ++m) {
    const int gmt = bc * 8 + 2 * w + m;
#pragma unroll
    for (int kk = 0; kk < 3; ++kk) {
      const int idx = ((gmt * 3 + kk) * 64 + lane) * 8;
      ah[m][kk] = *(const bf16x8*)(y0f + idx);
      al[m][kk] = *(const bf16x8*)(y0f + HPLANE + idx);
    }
  }

  const short* kt = ws + KTAB + t * KSLOT;
  f32x4 acc[2][5];
#pragma unroll
  for (int m = 0; m < 2; ++m)
#pragma unroll
    for (int nt = 0; nt < 5; ++nt) acc[m][nt] = (f32x4){0.f, 0.f, 0.f, 0.f};

#pragma unroll
  for (int kk = 0; kk < 3; ++kk) {
#pragma unroll
    for (int nt = 0; nt < 5; ++nt) {
      const bf16x8 bh = *(const bf16x8*)(kt + ((kk * 5 + nt) * 64 + lane) * 8);
      const bf16x8 bl = *(const bf16x8*)(kt + 7680 + ((kk * 5 + nt) * 64 + lane) * 8);
#pragma unroll
      for (int m = 0; m < 2; ++m) {
        acc[m][nt] = MFMA(ah[m][kk], bh, acc[m][nt], 0, 0, 0);
        acc[m][nt] = MFMA(al[m][kk], bh, acc[m][nt], 0, 0, 0);
        acc[m][nt] = MFMA(ah[m][kk], bl, acc[m][nt], 0, 0, 0);
      }
    }
  }
#pragma unroll
  for (int m = 0; m < 2; ++m)
#pragma unroll
    for (int nt = 0; nt < 5; ++nt)
#pragma unroll
      for (int r = 0; r < 4; ++r)
        yp[(b0 + (2 * w + m) * 16 + kg * 4 + r) * YROW + (long)t * 80 + nt * 16 + m16] =
            acc[m][nt][r];
}

// ---------------------------------------------------------------------------
// Fused kernel: 6144 blocks. bid%3==2 -> ypred block (write-BW bound),
// else -> mlp block (latency bound). 32768-B LDS -> 5 blocks/CU (20 waves).
// ---------------------------------------------------------------------------
__global__ __launch_bounds__(256, 4) void fused_kernel(const float* __restrict__ x,
                                                       const float* __restrict__ b1g,
                                                       const float* __restrict__ b2g,
                                                       const short* __restrict__ ws,
                                                       float* __restrict__ y,
                                                       float* __restrict__ yp) {
  extern __shared__ char smem[];
  const int bid = blockIdx.x;
  const int g = bid / 3;
  const int r = bid - 3 * g;
  if (r == 2) {
    ypred_body(g, ws, yp, threadIdx.x);
  } else {
    mlp_body<16, 0>((long)(g * 2 + r), x, b1g, b2g, ws, y, nullptr,
                    (short*)smem, threadIdx.x);
  }
}

extern "C" void kernel_launch(void* const* d_in, const int* in_sizes, int n_in,
                              void* d_out, int out_size, void* d_ws, size_t ws_size,
                              hipStream_t stream) {
  const float* x  = (const float*)d_in[0];
  const float* W1 = (const float*)d_in[1];
  const float* b1 = (const float*)d_in[2];
  const float* W2 = (const float*)d_in[3];
  const float* b2 = (const float*)d_in[4];
  const float* W3 = (const float*)d_in[5];
  const float* Kg = (const float*)d_in[6];
  float* y  = (float*)d_out;
  float* yp = y + (long)NB * YROW;
  short* ws = (short*)d_ws;

  prep_kernel<<<256, 256, 0, stream>>>(W1, W2, W3, ws);
  kpow_mlp0_kernel<<<79, 1024, 5 * FIMG_B, stream>>>(Kg, x, b1, b2, ws);
  fused_kernel<<<6144, 256, HBYTES, stream>>>(x, b1, b2, ws, y, yp);
}